// Round 2
// 21039.792 us; speedup vs baseline: 1.7915x; 1.7915x over previous
//
#include <hip/hip_runtime.h>
#include <cmath>

// ---------------- constants ----------------
static constexpr int QL_ = 512;   // qlen
static constexpr int KL_ = 1024;  // klen
static constexpr int BS_ = 16;    // bsz

// workspace offsets (in floats)
static constexpr size_t OFF_THEME = 0;                                   // 1000*1024
static constexpr size_t OFF_ROLE  = OFF_THEME + (size_t)1000*1024;       // 64*256
static constexpr size_t OFF_TCAT  = OFF_ROLE  + (size_t)64*256;          // 1000*512
static constexpr size_t OFF_POS   = OFF_TCAT  + (size_t)1000*512;        // 1024*1024
static constexpr size_t OFF_RH    = OFF_POS   + (size_t)1024*1024;       // 1024*1024
static constexpr size_t OFF_OUT   = OFF_RH    + (size_t)1024*1024;       // 512*16*1024
static constexpr size_t OFF_H     = OFF_OUT   + (size_t)512*16*1024;
static constexpr size_t OFF_T2    = OFF_H     + (size_t)512*16*1024;
static constexpr size_t OFF_VEC   = OFF_T2    + (size_t)512*16*1024;     // also LN1 output
static constexpr size_t OFF_POOL  = OFF_VEC   + (size_t)512*16*1024;     // 16*1024
static constexpr size_t OFF_HEADS = OFF_POOL  + (size_t)16*1024;         // 1024*16*3072 (also FFN1 buf)

// ---------------- small kernels ----------------
__global__ void k_role(const float* __restrict__ rel_r_f, const float* __restrict__ form_emb,
                       const float* __restrict__ role_emb, float* __restrict__ role)
{
    int r = blockIdx.x, c = threadIdx.x;
    float v;
    if (c < 128) v = role_emb[r*128 + c];
    else {
        v = 0.f; int cc = c - 128;
        #pragma unroll
        for (int k = 0; k < 32; ++k) v += rel_r_f[r*32 + k] * form_emb[k*128 + cc];
    }
    role[r*256 + c] = v;
}

__global__ void k_tcat(const float* __restrict__ rel_t_r, const float* __restrict__ role,
                       const float* __restrict__ theme_emb, float* __restrict__ tcat)
{
    int t = blockIdx.x, c = threadIdx.x;
    float v;
    if (c < 256) v = theme_emb[t*256 + c];
    else {
        v = 0.f; int cc = c - 256;
        for (int k = 0; k < 64; ++k) v += rel_t_r[t*64 + k] * role[k*256 + cc];
    }
    tcat[t*512 + c] = v;
}

__global__ void k_pos(float* __restrict__ pos)
{
    int gid = blockIdx.x*256 + threadIdx.x;   // 1024*1024 total
    int j = gid >> 10, dd = gid & 1023;
    float p = (float)(1023 - j);
    int x = (dd < 512) ? dd : (dd - 512);
    float invf = 1.0f / powf(10000.0f, (float)x * (1.0f/512.0f));
    float a = p * invf;
    pos[gid] = (dd < 512) ? sinf(a) : cosf(a);
}

__global__ void k_embed(const int* __restrict__ dec, const float* __restrict__ wemb,
                        float* __restrict__ out)
{
    int row = blockIdx.x;               // t*16+b
    int tok = dec[row];
    const float4 v = *(const float4*)(wemb + (size_t)tok*1024 + threadIdx.x*4);
    *(float4*)(out + (size_t)row*1024 + threadIdx.x*4) = v;
}

template<bool ADD>
__global__ void k_ln(const float* __restrict__ x, const float* __restrict__ y,
                     const float* __restrict__ g, const float* __restrict__ be,
                     float* __restrict__ o)
{
    __shared__ float red[256];
    const int row = blockIdx.x, tid = threadIdx.x;
    const size_t base = (size_t)row*1024 + tid*4;
    float4 xv = *(const float4*)(x + base);
    if (ADD) {
        float4 yv = *(const float4*)(y + base);
        xv.x += yv.x; xv.y += yv.y; xv.z += yv.z; xv.w += yv.w;
    }
    red[tid] = xv.x + xv.y + xv.z + xv.w;
    __syncthreads();
    for (int st = 128; st > 0; st >>= 1) { if (tid < st) red[tid] += red[tid+st]; __syncthreads(); }
    float mu = red[0] * (1.f/1024.f);
    __syncthreads();
    float dx = xv.x-mu, dy = xv.y-mu, dz = xv.z-mu, dw = xv.w-mu;
    red[tid] = dx*dx + dy*dy + dz*dz + dw*dw;
    __syncthreads();
    for (int st = 128; st > 0; st >>= 1) { if (tid < st) red[tid] += red[tid+st]; __syncthreads(); }
    float rstd = rsqrtf(red[0]*(1.f/1024.f) + 1e-3f);
    float4 gv = *(const float4*)(g + tid*4);
    float4 bv = *(const float4*)(be + tid*4);
    float4 ov;
    ov.x = dx*rstd*gv.x + bv.x;
    ov.y = dy*rstd*gv.y + bv.y;
    ov.z = dz*rstd*gv.z + bv.z;
    ov.w = dw*rstd*gv.w + bv.w;
    *(float4*)(o + base) = ov;
}

__global__ void k_pool(const int* __restrict__ dec, const float* __restrict__ out,
                       float* __restrict__ pooled)
{
    int gid = blockIdx.x*256 + threadIdx.x;   // 16*1024
    int b = gid >> 10, d = gid & 1023;
    float s = 0.f;
    for (int t = 0; t < 512; ++t) {
        float e = (dec[t*16 + b] == 2) ? 1.0f : 0.0f;
        s += e * out[((size_t)t*16 + b)*1024 + d];
    }
    pooled[gid] = s;
}

__global__ void k_logits(const float* __restrict__ pooled, const float* __restrict__ theme,
                         float* __restrict__ logits)
{
    int t = blockIdx.x;          // 1000 blocks, 64 threads
    int lane = threadIdx.x;
    float acc[16];
    #pragma unroll
    for (int b = 0; b < 16; ++b) acc[b] = 0.f;
    for (int d = lane; d < 1024; d += 64) {
        float tv = theme[(size_t)t*1024 + d];
        #pragma unroll
        for (int b = 0; b < 16; ++b) acc[b] += pooled[b*1024 + d] * tv;
    }
    #pragma unroll
    for (int b = 0; b < 16; ++b) {
        float v = acc[b];
        for (int m = 32; m >= 1; m >>= 1) v += __shfl_xor(v, m);
        if (lane == 0) logits[b*1000 + t] = v;
    }
}

// ---------------- split-bf16 MFMA GEMM ----------------
// C[M,N] = act(A[M,K] @ B[K,N] + bias) in near-fp32 precision via the
// 3-product bf16 split: A=Ah+Al, B=Bh+Bl, C ~= Ah*Bh + Ah*Bl + Al*Bh
// (dropped Al*Bl ~ 2^-16 relative). Effective peak 2495/3 ~ 830 TF vs
// 157 TF fp32 vector.
// 128x128 tile, BK=32, 256 threads = 4 waves in 2x2, each wave 64x64 via
// 4x4 fragments of mfma_f32_16x16x32_bf16.
typedef __attribute__((ext_vector_type(8))) short bf16x8;
typedef __attribute__((ext_vector_type(4))) float f32x4;

// truncate-split: hi = trunc-bf16(v); residual v-hi is exact in fp32;
// lo = trunc-bf16(residual). 4 VALU ops/element.
__device__ __forceinline__ void split2(float v, unsigned short& h, unsigned short& l)
{
    unsigned u = __float_as_uint(v);
    h = (unsigned short)(u >> 16);
    float r = v - __uint_as_float(u & 0xffff0000u);
    l = (unsigned short)(__float_as_uint(r) >> 16);
}

template<int ACT, bool BIAS, bool CAT>
__launch_bounds__(256, 2)
__global__ void gemm_mfma(const float* __restrict__ A, const float* __restrict__ A2, int M1,
                          const float* __restrict__ B, const float* __restrict__ bias,
                          float* __restrict__ C, int M, int N, int K)
{
    // A tiles: [row 0..127][k 0..31] bf16, row stride 32 elem (64B) — linear.
    //   staging writes (8B along k) and b128 fragment reads are both
    //   evenly bank-distributed at this stride (min-depth, no swizzle needed).
    // B tiles: [n 0..127][k 0..31] bf16 (transposed!), 8 chunks of 8B per row,
    //   chunk position XOR-swizzled with (n&7)^((n>>3)&7) so the transposing
    //   column writes AND the b64-pair fragment reads both spread across banks.
    __shared__ __align__(16) unsigned short As_hi[128*32];
    __shared__ __align__(16) unsigned short As_lo[128*32];
    __shared__ __align__(16) unsigned short Bs_hi[128*32];
    __shared__ __align__(16) unsigned short Bs_lo[128*32];

    const int tid = threadIdx.x;
    const int n0 = blockIdx.x * 128, m0 = blockIdx.y * 128;

    // staging assignments
    const int sa_row = tid >> 3;            // A: 32 rows per rep (x4 reps)
    const int sa_kc  = (tid & 7) << 2;      // A: k offset (float4 along k)
    const int sb_n   = tid & 127;           // B: column
    const int sb_kq  = tid >> 7;            // B: k-quad 0..1 (+2 per rep)
    const int sb_xm  = (sb_n & 7) ^ ((sb_n >> 3) & 7);

    float4 av[4];
    float  bv[4][4];

    auto loadA = [&](int k0) {
        #pragma unroll
        for (int rep = 0; rep < 4; ++rep) {
            int row = sa_row + (rep << 5);
            int gm  = m0 + row;
            float4 v = make_float4(0.f, 0.f, 0.f, 0.f);
            if (gm < M) {
                const float* src = A; int rr = gm;
                if (CAT) { if (gm >= M1) { src = A2; rr = gm - M1; } }
                v = *(const float4*)(src + (size_t)rr*K + k0 + sa_kc);
            }
            av[rep] = v;
        }
    };
    // B loaded column-wise: each thread grabs 4 k-consecutive values of one
    // column (4 coalesced dword loads across lanes), so the LDS write is a
    // contiguous 8B chunk along k.
    auto loadB = [&](int k0) {
        #pragma unroll
        for (int rep = 0; rep < 4; ++rep) {
            int kq = sb_kq + (rep << 1);
            const float* bp = B + (size_t)(k0 + (kq << 2))*N + n0 + sb_n;
            #pragma unroll
            for (int j = 0; j < 4; ++j) bv[rep][j] = bp[(size_t)j*N];
        }
    };
    auto store = [&]() {
        #pragma unroll
        for (int rep = 0; rep < 4; ++rep) {
            int row = sa_row + (rep << 5);
            int idx = row*32 + sa_kc;
            ushort4 h, l;
            split2(av[rep].x, h.x, l.x);
            split2(av[rep].y, h.y, l.y);
            split2(av[rep].z, h.z, l.z);
            split2(av[rep].w, h.w, l.w);
            *(ushort4*)(As_hi + idx) = h;
            *(ushort4*)(As_lo + idx) = l;
        }
        #pragma unroll
        for (int rep = 0; rep < 4; ++rep) {
            int kq  = sb_kq + (rep << 1);
            int idx = sb_n*32 + ((kq ^ sb_xm) << 2);
            ushort4 h, l;
            split2(bv[rep][0], h.x, l.x);
            split2(bv[rep][1], h.y, l.y);
            split2(bv[rep][2], h.z, l.z);
            split2(bv[rep][3], h.w, l.w);
            *(ushort4*)(Bs_hi + idx) = h;
            *(ushort4*)(Bs_lo + idx) = l;
        }
    };

    // fragment geometry (16x16x32 bf16):
    //   A/B operand: lane = (k>>3)*16 + i, holds 8 contiguous k
    //   C/D: col = lane&15, row = (lane>>4)*4 + reg      [m89-verified]
    const int lane = tid & 63;
    const int w    = tid >> 6;
    const int wm   = w >> 1, wn = w & 1;     // wave tile: rows wm*64, cols wn*64
    const int fr   = lane & 15;
    const int khi  = lane >> 4;

    int aoff[4], boff[4];
    #pragma unroll
    for (int mf = 0; mf < 4; ++mf)
        aoff[mf] = (wm*64 + mf*16 + fr)*32 + khi*8;
    #pragma unroll
    for (int nf = 0; nf < 4; ++nf) {
        int n  = wn*64 + nf*16 + fr;
        int xm = (n & 7) ^ ((n >> 3) & 7);
        boff[nf] = n*32 + ((((khi << 1) ^ xm)) << 2);   // chunk 2*khi (k 0..3); ^4 -> k 4..7
    }

    f32x4 acc[4][4] = {};

    const int nt = K >> 5;
    loadA(0); loadB(0);
    for (int t = 0; t < nt; ++t) {
        __syncthreads();           // prior tile's LDS reads done
        store();
        __syncthreads();
        if (t + 1 < nt) { loadA((t + 1) << 5); loadB((t + 1) << 5); }  // in flight under MFMAs

        bf16x8 ah[4], al[4], bh[4], bl[4];
        #pragma unroll
        for (int mf = 0; mf < 4; ++mf) {
            ah[mf] = *(const bf16x8*)(As_hi + aoff[mf]);
            al[mf] = *(const bf16x8*)(As_lo + aoff[mf]);
        }
        union BU { ushort4 q[2]; bf16x8 v; };
        #pragma unroll
        for (int nf = 0; nf < 4; ++nf) {
            BU uh, ul;
            uh.q[0] = *(const ushort4*)(Bs_hi + boff[nf]);
            uh.q[1] = *(const ushort4*)(Bs_hi + (boff[nf] ^ 4));
            ul.q[0] = *(const ushort4*)(Bs_lo + boff[nf]);
            ul.q[1] = *(const ushort4*)(Bs_lo + (boff[nf] ^ 4));
            bh[nf] = uh.v; bl[nf] = ul.v;
        }
        #pragma unroll
        for (int mf = 0; mf < 4; ++mf)
            #pragma unroll
            for (int nf = 0; nf < 4; ++nf) {
                acc[mf][nf] = __builtin_amdgcn_mfma_f32_16x16x32_bf16(ah[mf], bh[nf], acc[mf][nf], 0, 0, 0);
                acc[mf][nf] = __builtin_amdgcn_mfma_f32_16x16x32_bf16(ah[mf], bl[nf], acc[mf][nf], 0, 0, 0);
                acc[mf][nf] = __builtin_amdgcn_mfma_f32_16x16x32_bf16(al[mf], bh[nf], acc[mf][nf], 0, 0, 0);
            }
    }

    // epilogue
    const int cb = n0 + wn*64 + fr;
    #pragma unroll
    for (int nf = 0; nf < 4; ++nf) {
        const int gc = cb + nf*16;
        const float bb = BIAS ? bias[gc] : 0.f;
        #pragma unroll
        for (int mf = 0; mf < 4; ++mf) {
            #pragma unroll
            for (int j = 0; j < 4; ++j) {
                int gr = m0 + wm*64 + mf*16 + khi*4 + j;
                if (gr < M) {
                    float v = acc[mf][nf][j] + bb;
                    if (ACT == 1) v = tanhf(v);
                    if (ACT == 2) v = fmaxf(v, 0.f);
                    C[(size_t)gr*N + gc] = v;
                }
            }
        }
    }
}

// ---------------- fused attention (flash-style, rel-shift folded) ----------------
// block: (i-tile of 32, b, n); 256 threads = 8 row-groups(4 rows) x 32 col-groups(2 cols)
__device__ __forceinline__ int swz(int row, int c4) {
    return row*64 + ((c4 ^ (row & 15)) << 2);
}

__launch_bounds__(256)
__global__ void k_attn(const float* __restrict__ heads, const float* __restrict__ rh,
                       const float* __restrict__ rwb, const float* __restrict__ rrb,
                       const int* __restrict__ dec, float* __restrict__ vec)
{
    __shared__ float qw[33*64];     // q + r_w_bias, rows i0..i0+32
    __shared__ float kv_s[64*64];   // K tile (score phase), then V tile (PV phase); swizzled
    __shared__ float rt[96*64];     // shifted rh rows (score), then P (PV); swizzled/plain
    __shared__ float dif[64];       // rrb - rwb
    float* ps = rt;

    const int i0  = blockIdx.x * 32;
    const int b   = blockIdx.y;
    const int n   = blockIdx.z;
    const int tid = threadIdx.x;
    const int tx  = tid & 31;       // cols 2tx, 2tx+1
    const int ty  = tid >> 5;       // rows 4ty..4ty+3

    // stage qw (+ bias diff)
    for (int idx = tid; idx < 33*16; idx += 256) {
        int r = idx >> 4, c4 = idx & 15;
        int iq = i0 + r; if (iq > 511) iq = 511;
        float4 qv = *(const float4*)(heads + ((size_t)(512 + iq)*16 + b)*3072 + n*64 + (c4<<2));
        float4 wv = *(const float4*)(rwb + n*64 + (c4<<2));
        qv.x += wv.x; qv.y += wv.y; qv.z += wv.z; qv.w += wv.w;
        *(float4*)(qw + r*64 + (c4<<2)) = qv;
    }
    if (tid < 16) {
        float4 a = *(const float4*)(rrb + n*64 + (tid<<2));
        float4 c = *(const float4*)(rwb + n*64 + (tid<<2));
        a.x -= c.x; a.y -= c.y; a.z -= c.z; a.w -= c.w;
        *(float4*)(dif + (tid<<2)) = a;
    }

    float m_run[4], l_run[4], acc[4][2];
    #pragma unroll
    for (int q = 0; q < 4; ++q) { m_run[q] = -3.0e38f; l_run[q] = 0.f; acc[q][0] = 0.f; acc[q][1] = 0.f; }

    const int rbase = 2*tx - 4*ty + 28;

    for (int j0 = 0; j0 < 1024; j0 += 64) {
        __syncthreads();
        // stage K tile
        for (int idx = tid; idx < 64*16; idx += 256) {
            int jj = idx >> 4, c4 = idx & 15;
            float4 v = *(const float4*)(heads + ((size_t)(j0+jj)*16 + b)*3072 + 1024 + n*64 + (c4<<2));
            *(float4*)(kv_s + swz(jj, c4)) = v;
        }
        // stage shifted-rh tile: row rr holds rh for u = umin+rr (0 where rel_shift pads)
        const int umin = j0 - i0 - 31;
        for (int idx = tid; idx < 96*16; idx += 256) {
            int rr = idx >> 4, c4 = idx & 15;
            int u  = umin + rr;
            int jr = (u <= 512) ? (511 + u) : (u - 514);   // u==513 -> -1 -> zeros
            float4 v = make_float4(0.f, 0.f, 0.f, 0.f);
            if (jr >= 0 && jr < 1024)
                v = *(const float4*)(rh + (size_t)jr*1024 + n*64 + (c4<<2));
            *(float4*)(rt + swz(rr, c4)) = v;
        }
        __syncthreads();

        // scores: AC + BD
        float s0[4][2];
        #pragma unroll
        for (int q = 0; q < 4; ++q) { s0[q][0] = 0.f; s0[q][1] = 0.f; }
        const int u00 = (j0 + 2*tx) - (i0 + 4*ty);
        for (int c4 = 0; c4 < 16; ++c4) {
            float4 dv = *(const float4*)(dif + (c4<<2));
            float4 qv[5], qr[5];
            #pragma unroll
            for (int s5 = 0; s5 < 5; ++s5) {
                qv[s5] = *(const float4*)(qw + (4*ty+s5)*64 + (c4<<2));
                qr[s5].x = qv[s5].x + dv.x; qr[s5].y = qv[s5].y + dv.y;
                qr[s5].z = qv[s5].z + dv.z; qr[s5].w = qv[s5].w + dv.w;
            }
            float4 kk[2];
            kk[0] = *(const float4*)(kv_s + swz(2*tx,   c4));
            kk[1] = *(const float4*)(kv_s + swz(2*tx+1, c4));
            float4 rv[5];
            #pragma unroll
            for (int s5 = 0; s5 < 5; ++s5) rv[s5] = *(const float4*)(rt + swz(rbase + s5, c4));
            #pragma unroll
            for (int q = 0; q < 4; ++q) {
                #pragma unroll
                for (int p = 0; p < 2; ++p) {
                    float ac = qv[q].x*kk[p].x + qv[q].y*kk[p].y + qv[q].z*kk[p].z + qv[q].w*kk[p].w;
                    int u = u00 + p - q;
                    float4 qq = (u >= 514) ? qr[q+1] : qr[q];
                    float4 rr2 = rv[p - q + 3];
                    float bd = qq.x*rr2.x + qq.y*rr2.y + qq.z*rr2.z + qq.w*rr2.w;
                    s0[q][p] += ac + bd;
                }
            }
        }
        // scale + key mask
        float sc[4][2];
        #pragma unroll
        for (int p = 0; p < 2; ++p) {
            int j = j0 + 2*tx + p;
            bool masked = (j >= 512) && (dec[(j-512)*16 + b] == 0);
            #pragma unroll
            for (int q = 0; q < 4; ++q) sc[q][p] = masked ? -1.0e9f : s0[q][p] * 0.125f;
        }
        __syncthreads();   // K/rh reads done -> reuse LDS
        // stage V tile into kv_s
        for (int idx = tid; idx < 64*16; idx += 256) {
            int jj = idx >> 4, c4 = idx & 15;
            float4 v = *(const float4*)(heads + ((size_t)(j0+jj)*16 + b)*3072 + 2048 + n*64 + (c4<<2));
            *(float4*)(kv_s + swz(jj, c4)) = v;
        }
        // online softmax; write P into ps (rt region, plain layout)
        #pragma unroll
        for (int q = 0; q < 4; ++q) {
            float tmax = fmaxf(sc[q][0], sc[q][1]);
            for (int msk = 16; msk >= 1; msk >>= 1) tmax = fmaxf(tmax, __shfl_xor(tmax, msk));
            float mnew  = fmaxf(m_run[q], tmax);
            float alpha = expf(m_run[q] - mnew);
            float p0 = expf(sc[q][0] - mnew);
            float p1 = expf(sc[q][1] - mnew);
            float tsum = p0 + p1;
            for (int msk = 16; msk >= 1; msk >>= 1) tsum += __shfl_xor(tsum, msk);
            l_run[q] = l_run[q]*alpha + tsum;
            m_run[q] = mnew;
            acc[q][0] *= alpha; acc[q][1] *= alpha;
            *(float2*)(ps + (4*ty+q)*64 + 2*tx) = make_float2(p0, p1);
        }
        __syncthreads();
        // PV
        for (int j = 0; j < 64; ++j) {
            float2 vv = *(const float2*)(kv_s + swz(j, tx >> 1) + ((2*tx) & 3));
            #pragma unroll
            for (int q = 0; q < 4; ++q) {
                float pq = ps[(4*ty+q)*64 + j];
                acc[q][0] += pq * vv.x;
                acc[q][1] += pq * vv.y;
            }
        }
    }
    #pragma unroll
    for (int q = 0; q < 4; ++q) {
        int i = i0 + 4*ty + q;
        float inv = 1.0f / l_run[q];
        *(float2*)(vec + ((size_t)i*16 + b)*1024 + n*64 + 2*tx) =
            make_float2(acc[q][0]*inv, acc[q][1]*inv);
    }
}

// ---------------- launch ----------------
extern "C" void kernel_launch(void* const* d_in, const int* in_sizes, int n_in,
                              void* d_out, int out_size, void* d_ws, size_t ws_size,
                              hipStream_t stream)
{
    (void)in_sizes; (void)n_in; (void)out_size; (void)ws_size;
    const int*   dec       = (const int*)  d_in[0];
    const float* mems      = (const float*)d_in[1];
    const float* rel_t_r   = (const float*)d_in[2];
    const float* rel_r_f   = (const float*)d_in[3];
    const float* theme_emb = (const float*)d_in[4];
    const float* role_emb  = (const float*)d_in[5];
    const float* form_emb  = (const float*)d_in[6];
    const float* word_emb  = (const float*)d_in[7];
    const float* theme_W   = (const float*)d_in[8];
    const float* theme_b   = (const float*)d_in[9];
    const float* r_w_bias  = (const float*)d_in[10];
    const float* r_r_bias  = (const float*)d_in[11];
    const float* qkv_W     = (const float*)d_in[12];
    const float* qkv_b     = (const float*)d_in[13];
    const float* r_W       = (const float*)d_in[14];
    const float* o_W       = (const float*)d_in[15];
    const float* o_b       = (const float*)d_in[16];
    const float* ln_att_g  = (const float*)d_in[17];
    const float* ln_att_b  = (const float*)d_in[18];
    const float* ln1_g     = (const float*)d_in[19];
    const float* ln1_b     = (const float*)d_in[20];
    const float* ffn_W1    = (const float*)d_in[21];
    const float* ffn_b1    = (const float*)d_in[22];
    const float* ffn_W2    = (const float*)d_in[23];
    const float* ffn_b2    = (const float*)d_in[24];
    const float* ln2_g     = (const float*)d_in[25];
    const float* ln2_b     = (const float*)d_in[26];

    float* ws      = (float*)d_ws;
    float* logits  = (float*)d_out;
    float* w_theme = ws + OFF_THEME;
    float* w_role  = ws + OFF_ROLE;
    float* w_tcat  = ws + OFF_TCAT;
    float* w_pos   = ws + OFF_POS;
    float* w_rh    = ws + OFF_RH;
    float* w_out   = ws + OFF_OUT;
    float* w_h     = ws + OFF_H;
    float* w_t2    = ws + OFF_T2;
    float* w_vec   = ws + OFF_VEC;
    float* w_pool  = ws + OFF_POOL;
    float* w_heads = ws + OFF_HEADS;

    // theme pipeline
    k_role<<<64, 256, 0, stream>>>(rel_r_f, form_emb, role_emb, w_role);
    k_tcat<<<1000, 512, 0, stream>>>(rel_t_r, w_role, theme_emb, w_tcat);
    gemm_mfma<1, true, false><<<dim3(8, 8), 256, 0, stream>>>(
        w_tcat, nullptr, 0, theme_W, theme_b, w_theme, 1000, 1024, 512);

    k_pos<<<4096, 256, 0, stream>>>(w_pos);
    k_embed<<<8192, 256, 0, stream>>>(dec, word_emb, w_out);

    for (int i = 0; i < 8; ++i) {
        const float* memi = mems + (size_t)i*512*16*1024;
        // QKV (concat(mems, out) fused into A-load)
        gemm_mfma<0, true, true><<<dim3(24, 128), 256, 0, stream>>>(
            memi, w_out, 8192, qkv_W + (size_t)i*1024*3072, qkv_b + (size_t)i*3072,
            w_heads, 16384, 3072, 1024);
        // rh = pos @ r_W
        gemm_mfma<0, false, false><<<dim3(8, 8), 256, 0, stream>>>(
            w_pos, nullptr, 0, r_W + (size_t)i*1024*1024, nullptr, w_rh, 1024, 1024, 1024);
        // fused attention -> vec
        k_attn<<<dim3(16, 16, 16), 256, 0, stream>>>(w_heads, w_rh, r_w_bias, r_r_bias, dec, w_vec);
        // out-proj
        gemm_mfma<0, true, false><<<dim3(8, 64), 256, 0, stream>>>(
            w_vec, nullptr, 0, o_W + (size_t)i*1024*1024, o_b + (size_t)i*1024,
            w_t2, 8192, 1024, 1024);
        // h = LN(out + att)
        k_ln<true><<<8192, 256, 0, stream>>>(w_out, w_t2, ln_att_g + i*1024, ln_att_b + i*1024, w_h);
        // t = LN(h)   (reuse vec buffer)
        k_ln<false><<<8192, 256, 0, stream>>>(w_h, nullptr, ln1_g + i*1024, ln1_b + i*1024, w_vec);
        // FFN1 (relu) into heads buffer
        gemm_mfma<2, true, false><<<dim3(32, 64), 256, 0, stream>>>(
            w_vec, nullptr, 0, ffn_W1 + (size_t)i*1024*4096, ffn_b1 + (size_t)i*4096,
            w_heads, 8192, 4096, 1024);
        // FFN2
        gemm_mfma<0, true, false><<<dim3(8, 64), 256, 0, stream>>>(
            w_heads, nullptr, 0, ffn_W2 + (size_t)i*4096*1024, ffn_b2 + (size_t)i*1024,
            w_t2, 8192, 1024, 4096);
        // out = LN(h + t)
        k_ln<true><<<8192, 256, 0, stream>>>(w_h, w_t2, ln2_g + i*1024, ln2_b + i*1024, w_out);
    }

    k_pool<<<64, 256, 0, stream>>>(dec, w_out, w_pool);
    k_logits<<<1000, 64, 0, stream>>>(w_pool, w_theme, logits);
}

// Round 3
// 15999.899 us; speedup vs baseline: 2.3558x; 1.3150x over previous
//
#include <hip/hip_runtime.h>
#include <cmath>

// ---------------- workspace offsets (floats) ----------------
static constexpr size_t OFF_THEME = 0;                                   // 1000*1024
static constexpr size_t OFF_ROLE  = OFF_THEME + (size_t)1000*1024;       // 64*256
static constexpr size_t OFF_TCAT  = OFF_ROLE  + (size_t)64*256;          // 1000*512
static constexpr size_t OFF_POS   = OFF_TCAT  + (size_t)1000*512;        // 1024*1024
static constexpr size_t OFF_RH    = OFF_POS   + (size_t)1024*1024;       // (unused now)
static constexpr size_t OFF_OUT   = OFF_RH    + (size_t)1024*1024;       // 512*16*1024
static constexpr size_t OFF_H     = OFF_OUT   + (size_t)512*16*1024;     // also K2-packed lower half
static constexpr size_t OFF_T2    = OFF_H     + (size_t)512*16*1024;     // also K2-packed upper half
static constexpr size_t OFF_VEC   = OFF_T2    + (size_t)512*16*1024;
static constexpr size_t OFF_POOL  = OFF_VEC   + (size_t)512*16*1024;
static constexpr size_t OFF_HEADS = OFF_POOL  + (size_t)16*1024;         // 1024*16*3072
static constexpr size_t OFF_RH2   = OFF_HEADS + (size_t)1024*16*3072;    // 1024*1024 u32 (packed rh)

typedef __attribute__((ext_vector_type(8))) short bf16x8;
typedef __attribute__((ext_vector_type(4))) float f32x4;

__device__ __forceinline__ void split2(float v, unsigned short& h, unsigned short& l)
{
    unsigned u = __float_as_uint(v);
    h = (unsigned short)(u >> 16);
    float r = v - __uint_as_float(u & 0xffff0000u);
    l = (unsigned short)(__float_as_uint(r) >> 16);
}

// ---------------- small kernels ----------------
__global__ void k_role(const float* __restrict__ rel_r_f, const float* __restrict__ form_emb,
                       const float* __restrict__ role_emb, float* __restrict__ role)
{
    int r = blockIdx.x, c = threadIdx.x;
    float v;
    if (c < 128) v = role_emb[r*128 + c];
    else {
        v = 0.f; int cc = c - 128;
        #pragma unroll
        for (int k = 0; k < 32; ++k) v += rel_r_f[r*32 + k] * form_emb[k*128 + cc];
    }
    role[r*256 + c] = v;
}

__global__ void k_tcat(const float* __restrict__ rel_t_r, const float* __restrict__ role,
                       const float* __restrict__ theme_emb, float* __restrict__ tcat)
{
    int t = blockIdx.x, c = threadIdx.x;
    float v;
    if (c < 256) v = theme_emb[t*256 + c];
    else {
        v = 0.f; int cc = c - 256;
        for (int k = 0; k < 64; ++k) v += rel_t_r[t*64 + k] * role[k*256 + cc];
    }
    tcat[t*512 + c] = v;
}

__global__ void k_pos(float* __restrict__ pos)
{
    int gid = blockIdx.x*256 + threadIdx.x;
    int j = gid >> 10, dd = gid & 1023;
    float p = (float)(1023 - j);
    int x = (dd < 512) ? dd : (dd - 512);
    float invf = 1.0f / powf(10000.0f, (float)x * (1.0f/512.0f));
    float a = p * invf;
    pos[gid] = (dd < 512) ? sinf(a) : cosf(a);
}

__global__ void k_embed(const int* __restrict__ dec, const float* __restrict__ wemb,
                        float* __restrict__ out)
{
    int row = blockIdx.x;
    int tok = dec[row];
    const float4 v = *(const float4*)(wemb + (size_t)tok*1024 + threadIdx.x*4);
    *(float4*)(out + (size_t)row*1024 + threadIdx.x*4) = v;
}

template<bool ADD>
__global__ void k_ln(const float* __restrict__ x, const float* __restrict__ y,
                     const float* __restrict__ g, const float* __restrict__ be,
                     float* __restrict__ o)
{
    __shared__ float red[256];
    const int row = blockIdx.x, tid = threadIdx.x;
    const size_t base = (size_t)row*1024 + tid*4;
    float4 xv = *(const float4*)(x + base);
    if (ADD) {
        float4 yv = *(const float4*)(y + base);
        xv.x += yv.x; xv.y += yv.y; xv.z += yv.z; xv.w += yv.w;
    }
    red[tid] = xv.x + xv.y + xv.z + xv.w;
    __syncthreads();
    for (int st = 128; st > 0; st >>= 1) { if (tid < st) red[tid] += red[tid+st]; __syncthreads(); }
    float mu = red[0] * (1.f/1024.f);
    __syncthreads();
    float dx = xv.x-mu, dy = xv.y-mu, dz = xv.z-mu, dw = xv.w-mu;
    red[tid] = dx*dx + dy*dy + dz*dz + dw*dw;
    __syncthreads();
    for (int st = 128; st > 0; st >>= 1) { if (tid < st) red[tid] += red[tid+st]; __syncthreads(); }
    float rstd = rsqrtf(red[0]*(1.f/1024.f) + 1e-3f);
    float4 gv = *(const float4*)(g + tid*4);
    float4 bv = *(const float4*)(be + tid*4);
    float4 ov;
    ov.x = dx*rstd*gv.x + bv.x;
    ov.y = dy*rstd*gv.y + bv.y;
    ov.z = dz*rstd*gv.z + bv.z;
    ov.w = dw*rstd*gv.w + bv.w;
    *(float4*)(o + base) = ov;
}

__global__ void k_pool(const int* __restrict__ dec, const float* __restrict__ out,
                       float* __restrict__ pooled)
{
    int gid = blockIdx.x*256 + threadIdx.x;
    int b = gid >> 10, d = gid & 1023;
    float s = 0.f;
    for (int t = 0; t < 512; ++t) {
        float e = (dec[t*16 + b] == 2) ? 1.0f : 0.0f;
        s += e * out[((size_t)t*16 + b)*1024 + d];
    }
    pooled[gid] = s;
}

__global__ void k_logits(const float* __restrict__ pooled, const float* __restrict__ theme,
                         float* __restrict__ logits)
{
    int t = blockIdx.x;
    int lane = threadIdx.x;
    float acc[16];
    #pragma unroll
    for (int b = 0; b < 16; ++b) acc[b] = 0.f;
    for (int d = lane; d < 1024; d += 64) {
        float tv = theme[(size_t)t*1024 + d];
        #pragma unroll
        for (int b = 0; b < 16; ++b) acc[b] += pooled[b*1024 + d] * tv;
    }
    #pragma unroll
    for (int b = 0; b < 16; ++b) {
        float v = acc[b];
        for (int m = 32; m >= 1; m >>= 1) v += __shfl_xor(v, m);
        if (lane == 0) logits[b*1000 + t] = v;
    }
}

// ---------------- split-bf16 MFMA GEMM ----------------
// OMODE: 0 = fp32 C; 1 = all cols packed bf16 hi/lo into Cpk (u32, stride N);
//        2 = QKV mixed: cols [1024,2048) packed into Cpk (stride 1024), rest fp32 C.
template<int ACT, bool BIAS, bool CAT, int OMODE>
__launch_bounds__(256, 2)
__global__ void gemm_mfma(const float* __restrict__ A, const float* __restrict__ A2, int M1,
                          const float* __restrict__ B, const float* __restrict__ bias,
                          float* __restrict__ C, unsigned* __restrict__ Cpk,
                          int M, int N, int K)
{
    __shared__ __align__(16) unsigned short As_hi[128*32];
    __shared__ __align__(16) unsigned short As_lo[128*32];
    __shared__ __align__(16) unsigned short Bs_hi[128*32];
    __shared__ __align__(16) unsigned short Bs_lo[128*32];

    const int tid = threadIdx.x;
    const int n0 = blockIdx.x * 128, m0 = blockIdx.y * 128;

    const int sa_row = tid >> 3;
    const int sa_kc  = (tid & 7) << 2;
    const int sb_n   = tid & 127;
    const int sb_kq  = tid >> 7;
    const int sb_xm  = (sb_n & 7) ^ ((sb_n >> 3) & 7);

    float4 av[4];
    float  bv[4][4];

    auto loadA = [&](int k0) {
        #pragma unroll
        for (int rep = 0; rep < 4; ++rep) {
            int row = sa_row + (rep << 5);
            int gm  = m0 + row;
            float4 v = make_float4(0.f, 0.f, 0.f, 0.f);
            if (gm < M) {
                const float* src = A; int rr = gm;
                if (CAT) { if (gm >= M1) { src = A2; rr = gm - M1; } }
                v = *(const float4*)(src + (size_t)rr*K + k0 + sa_kc);
            }
            av[rep] = v;
        }
    };
    auto loadB = [&](int k0) {
        #pragma unroll
        for (int rep = 0; rep < 4; ++rep) {
            int kq = sb_kq + (rep << 1);
            const float* bp = B + (size_t)(k0 + (kq << 2))*N + n0 + sb_n;
            #pragma unroll
            for (int j = 0; j < 4; ++j) bv[rep][j] = bp[(size_t)j*N];
        }
    };
    auto store = [&]() {
        #pragma unroll
        for (int rep = 0; rep < 4; ++rep) {
            int row = sa_row + (rep << 5);
            int idx = row*32 + sa_kc;
            ushort4 h, l;
            split2(av[rep].x, h.x, l.x);
            split2(av[rep].y, h.y, l.y);
            split2(av[rep].z, h.z, l.z);
            split2(av[rep].w, h.w, l.w);
            *(ushort4*)(As_hi + idx) = h;
            *(ushort4*)(As_lo + idx) = l;
        }
        #pragma unroll
        for (int rep = 0; rep < 4; ++rep) {
            int kq  = sb_kq + (rep << 1);
            int idx = sb_n*32 + ((kq ^ sb_xm) << 2);
            ushort4 h, l;
            split2(bv[rep][0], h.x, l.x);
            split2(bv[rep][1], h.y, l.y);
            split2(bv[rep][2], h.z, l.z);
            split2(bv[rep][3], h.w, l.w);
            *(ushort4*)(Bs_hi + idx) = h;
            *(ushort4*)(Bs_lo + idx) = l;
        }
    };

    const int lane = tid & 63;
    const int w    = tid >> 6;
    const int wm   = w >> 1, wn = w & 1;
    const int fr   = lane & 15;
    const int khi  = lane >> 4;

    int aoff[4], boff[4];
    #pragma unroll
    for (int mf = 0; mf < 4; ++mf)
        aoff[mf] = (wm*64 + mf*16 + fr)*32 + khi*8;
    #pragma unroll
    for (int nf = 0; nf < 4; ++nf) {
        int n  = wn*64 + nf*16 + fr;
        int xm = (n & 7) ^ ((n >> 3) & 7);
        boff[nf] = n*32 + ((((khi << 1) ^ xm)) << 2);
    }

    f32x4 acc[4][4] = {};

    const int nt = K >> 5;
    loadA(0); loadB(0);
    for (int t = 0; t < nt; ++t) {
        __syncthreads();
        store();
        __syncthreads();
        if (t + 1 < nt) { loadA((t + 1) << 5); loadB((t + 1) << 5); }

        bf16x8 ah[4], al[4], bh[4], bl[4];
        #pragma unroll
        for (int mf = 0; mf < 4; ++mf) {
            ah[mf] = *(const bf16x8*)(As_hi + aoff[mf]);
            al[mf] = *(const bf16x8*)(As_lo + aoff[mf]);
        }
        union BU { ushort4 q[2]; bf16x8 v; };
        #pragma unroll
        for (int nf = 0; nf < 4; ++nf) {
            BU uh, ul;
            uh.q[0] = *(const ushort4*)(Bs_hi + boff[nf]);
            uh.q[1] = *(const ushort4*)(Bs_hi + (boff[nf] ^ 4));
            ul.q[0] = *(const ushort4*)(Bs_lo + boff[nf]);
            ul.q[1] = *(const ushort4*)(Bs_lo + (boff[nf] ^ 4));
            bh[nf] = uh.v; bl[nf] = ul.v;
        }
        #pragma unroll
        for (int mf = 0; mf < 4; ++mf)
            #pragma unroll
            for (int nf = 0; nf < 4; ++nf) {
                acc[mf][nf] = __builtin_amdgcn_mfma_f32_16x16x32_bf16(ah[mf], bh[nf], acc[mf][nf], 0, 0, 0);
                acc[mf][nf] = __builtin_amdgcn_mfma_f32_16x16x32_bf16(ah[mf], bl[nf], acc[mf][nf], 0, 0, 0);
                acc[mf][nf] = __builtin_amdgcn_mfma_f32_16x16x32_bf16(al[mf], bh[nf], acc[mf][nf], 0, 0, 0);
            }
    }

    const int cb = n0 + wn*64 + fr;
    #pragma unroll
    for (int nf = 0; nf < 4; ++nf) {
        const int gc = cb + nf*16;
        const float bb = BIAS ? bias[gc] : 0.f;
        #pragma unroll
        for (int mf = 0; mf < 4; ++mf) {
            #pragma unroll
            for (int j = 0; j < 4; ++j) {
                int gr = m0 + wm*64 + mf*16 + khi*4 + j;
                if (gr < M) {
                    float v = acc[mf][nf][j] + bb;
                    if (ACT == 1) v = tanhf(v);
                    if (ACT == 2) v = fmaxf(v, 0.f);
                    if (OMODE == 1) {
                        unsigned short h, l; split2(v, h, l);
                        Cpk[(size_t)gr*N + gc] = ((unsigned)h << 16) | l;
                    } else if (OMODE == 2 && gc >= 1024 && gc < 2048) {
                        unsigned short h, l; split2(v, h, l);
                        Cpk[(size_t)gr*1024 + (gc - 1024)] = ((unsigned)h << 16) | l;
                    } else {
                        C[(size_t)gr*N + gc] = v;
                    }
                }
            }
        }
    }
}

// ---------------- MFMA fused attention ----------------
// Block: (i-tile of 32, b, n); 128 threads = 2 waves. Wave w owns query cols
// i = i0 + 16w + (lane&15). All matmuls via swapped-operand MFMA so each lane
// owns one query column: S^T = K·Qw^T, G^T = rt·Qr^T, O^T = V^T·P^T.
// BD[i,j] = qr_{i+(u>=514)} . rt[u - umin] gathered from G in LDS (rel-shift folded,
// identical indexing to the previously-verified scalar kernel).
__launch_bounds__(128, 1)
__global__ void k_attn(const float* __restrict__ heads, const unsigned* __restrict__ k2pk,
                       const unsigned* __restrict__ rh2pk,
                       const float* __restrict__ rwb, const float* __restrict__ rrb,
                       const int* __restrict__ dec, float* __restrict__ vec)
{
    // LDS carve-up (62368 B):
    //  [0,16384)      K pair [64][64] u16 (hi,lo) -- phase 3 reuses as V fp32 [64][64]
    //  [16384,40960)  rt pair [96][64] u16        -- phase 3c/4 reuses as V pair, stride 68
    //  [40960,53896)  gq: qw fp32 [48][64] (preamble) then G fp32 [33][98]
    //  [53904,62096)  P pair [32][64] u16
    //  [62096,62352)  dec slice [64] int
    __shared__ __align__(16) char smem[62368];
    unsigned short* kvH = (unsigned short*)(smem);
    unsigned short* kvL = (unsigned short*)(smem + 8192);
    unsigned short* rtH = (unsigned short*)(smem + 16384);
    unsigned short* rtL = (unsigned short*)(smem + 28672);
    float*          gq  = (float*)(smem + 40960);
    unsigned short* pH  = (unsigned short*)(smem + 53904);
    unsigned short* pL  = (unsigned short*)(smem + 58000);
    int*            sdec= (int*)(smem + 62096);
    float*          vf  = (float*)smem;

    const int i0  = blockIdx.x * 32;
    const int b   = blockIdx.y;
    const int n   = blockIdx.z;
    const int tid = threadIdx.x;
    const int w   = tid >> 6;
    const int lane= tid & 63;
    const int lhi = lane >> 4, llo = lane & 15;
    const int iloc= 16*w + llo;          // this lane's query column (local)

    // ---- preamble: qw = q + rwb, 48 rows (clamped), fp32 into gq
    for (int idx = tid; idx < 48*16; idx += 128) {
        int r = idx >> 4, c4 = idx & 15;
        int iq = i0 + r; if (iq > 511) iq = 511;
        float4 qv = *(const float4*)(heads + ((size_t)(512 + iq)*16 + b)*3072 + n*64 + c4*4);
        float4 wv = *(const float4*)(rwb + n*64 + c4*4);
        qv.x += wv.x; qv.y += wv.y; qv.z += wv.z; qv.w += wv.w;
        *(float4*)(gq + r*64 + c4*4) = qv;
    }
    __syncthreads();

    // build Q B-operand fragments (held in registers through the j-loop)
    bf16x8 qwBh[2], qwBl[2], qrBh[3][2], qrBl[3][2];
    #pragma unroll
    for (int kc = 0; kc < 2; ++kc) {
        const int dbase = kc*32 + lhi*8;
        float4 r0 = *(const float4*)(rrb + n*64 + dbase);
        float4 r1 = *(const float4*)(rrb + n*64 + dbase + 4);
        float4 w0 = *(const float4*)(rwb + n*64 + dbase);
        float4 w1 = *(const float4*)(rwb + n*64 + dbase + 4);
        float dif[8] = {r0.x-w0.x, r0.y-w0.y, r0.z-w0.z, r0.w-w0.w,
                        r1.x-w1.x, r1.y-w1.y, r1.z-w1.z, r1.w-w1.w};
        {
            const float* qp = gq + (16*w + llo)*64 + dbase;
            float4 a0 = *(const float4*)qp, a1 = *(const float4*)(qp + 4);
            float q8[8] = {a0.x,a0.y,a0.z,a0.w,a1.x,a1.y,a1.z,a1.w};
            bf16x8 h, l;
            #pragma unroll
            for (int e = 0; e < 8; ++e) {
                unsigned short hh, ll; split2(q8[e], hh, ll);
                h[e] = (short)hh; l[e] = (short)ll;
            }
            qwBh[kc] = h; qwBl[kc] = l;
        }
        #pragma unroll
        for (int rf = 0; rf < 3; ++rf) {
            const float* qp = gq + (16*rf + llo)*64 + dbase;
            float4 a0 = *(const float4*)qp, a1 = *(const float4*)(qp + 4);
            float q8[8] = {a0.x,a0.y,a0.z,a0.w,a1.x,a1.y,a1.z,a1.w};
            bf16x8 h, l;
            #pragma unroll
            for (int e = 0; e < 8; ++e) {
                unsigned short hh, ll; split2(q8[e] + dif[e], hh, ll);
                h[e] = (short)hh; l[e] = (short)ll;
            }
            qrBh[rf][kc] = h; qrBl[rf][kc] = l;
        }
    }

    float m_run = -3.0e38f, l_run = 0.f;
    f32x4 acc_o[4] = {};

    for (int j0 = 0; j0 < 1024; j0 += 64) {
        const int umin = j0 - i0 - 31;
        __syncthreads();                       // prior iteration's LDS reads done
        // ---- phase 1: stage K pair, rt pair, dec
        #pragma unroll
        for (int it = 0; it < 4; ++it) {
            int jj = it*16 + (tid >> 3), c = tid & 7;
            const unsigned* src = k2pk + ((size_t)(j0 + jj)*16 + b)*1024 + n*64 + c*8;
            uint4 v0 = *(const uint4*)src, v1 = *(const uint4*)(src + 4);
            bf16x8 h8, l8;
            h8[0]=(short)(v0.x>>16); l8[0]=(short)(v0.x&0xffffu);
            h8[1]=(short)(v0.y>>16); l8[1]=(short)(v0.y&0xffffu);
            h8[2]=(short)(v0.z>>16); l8[2]=(short)(v0.z&0xffffu);
            h8[3]=(short)(v0.w>>16); l8[3]=(short)(v0.w&0xffffu);
            h8[4]=(short)(v1.x>>16); l8[4]=(short)(v1.x&0xffffu);
            h8[5]=(short)(v1.y>>16); l8[5]=(short)(v1.y&0xffffu);
            h8[6]=(short)(v1.z>>16); l8[6]=(short)(v1.z&0xffffu);
            h8[7]=(short)(v1.w>>16); l8[7]=(short)(v1.w&0xffffu);
            int idx = jj*64 + ((c ^ (jj & 7)) << 3);
            *(bf16x8*)(kvH + idx) = h8; *(bf16x8*)(kvL + idx) = l8;
        }
        #pragma unroll
        for (int it = 0; it < 6; ++it) {
            int rr = it*16 + (tid >> 3), c = tid & 7;
            int u = umin + rr;
            int jr = (u <= 512) ? (511 + u) : (u - 514);
            bf16x8 h8 = {0,0,0,0,0,0,0,0}, l8 = {0,0,0,0,0,0,0,0};
            if (jr >= 0 && jr < 1024) {
                const unsigned* src = rh2pk + (size_t)jr*1024 + n*64 + c*8;
                uint4 v0 = *(const uint4*)src, v1 = *(const uint4*)(src + 4);
                h8[0]=(short)(v0.x>>16); l8[0]=(short)(v0.x&0xffffu);
                h8[1]=(short)(v0.y>>16); l8[1]=(short)(v0.y&0xffffu);
                h8[2]=(short)(v0.z>>16); l8[2]=(short)(v0.z&0xffffu);
                h8[3]=(short)(v0.w>>16); l8[3]=(short)(v0.w&0xffffu);
                h8[4]=(short)(v1.x>>16); l8[4]=(short)(v1.x&0xffffu);
                h8[5]=(short)(v1.y>>16); l8[5]=(short)(v1.y&0xffffu);
                h8[6]=(short)(v1.z>>16); l8[6]=(short)(v1.z&0xffffu);
                h8[7]=(short)(v1.w>>16); l8[7]=(short)(v1.w&0xffffu);
            }
            int idx = rr*64 + ((c ^ (rr & 7)) << 3);
            *(bf16x8*)(rtH + idx) = h8; *(bf16x8*)(rtL + idx) = l8;
        }
        if (j0 >= 512 && tid < 64) sdec[tid] = dec[(j0 - 512 + tid)*16 + b];
        __syncthreads();

        // ---- phase 2: AC (S^T) and G^T MFMA
        f32x4 accs[4] = {};
        f32x4 accg[3][3] = {};
        #pragma unroll
        for (int kc = 0; kc < 2; ++kc) {
            const int cc = kc*4 + lhi;
            #pragma unroll
            for (int jf = 0; jf < 4; ++jf) {
                int row = 16*jf + llo;
                int idx = row*64 + ((cc ^ (row & 7)) << 3);
                bf16x8 ah = *(const bf16x8*)(kvH + idx);
                bf16x8 al = *(const bf16x8*)(kvL + idx);
                accs[jf] = __builtin_amdgcn_mfma_f32_16x16x32_bf16(ah, qwBh[kc], accs[jf], 0, 0, 0);
                accs[jf] = __builtin_amdgcn_mfma_f32_16x16x32_bf16(ah, qwBl[kc], accs[jf], 0, 0, 0);
                accs[jf] = __builtin_amdgcn_mfma_f32_16x16x32_bf16(al, qwBh[kc], accs[jf], 0, 0, 0);
            }
            #pragma unroll
            for (int uf = 0; uf < 3; ++uf) {
                int row = (3*w + uf)*16 + llo;
                int idx = row*64 + ((cc ^ (row & 7)) << 3);
                bf16x8 ah = *(const bf16x8*)(rtH + idx);
                bf16x8 al = *(const bf16x8*)(rtL + idx);
                #pragma unroll
                for (int rf = 0; rf < 3; ++rf) {
                    accg[uf][rf] = __builtin_amdgcn_mfma_f32_16x16x32_bf16(ah, qrBh[rf][kc], accg[uf][rf], 0, 0, 0);
                    accg[uf][rf] = __builtin_amdgcn_mfma_f32_16x16x32_bf16(ah, qrBl[rf][kc], accg[uf][rf], 0, 0, 0);
                    accg[uf][rf] = __builtin_amdgcn_mfma_f32_16x16x32_bf16(al, qrBh[rf][kc], accg[uf][rf], 0, 0, 0);
                }
            }
        }
        // write G (rows 0..32 only; stride 98 breaks bank aliasing)
        #pragma unroll
        for (int uf = 0; uf < 3; ++uf)
            #pragma unroll
            for (int rf = 0; rf < 3; ++rf) {
                if (rf == 2 && llo != 0) continue;
                int r  = 16*rf + llo;
                int uc = (3*w + uf)*16 + lhi*4;
                float* gp = gq + r*98 + uc;
                gp[0] = accg[uf][rf][0]; gp[1] = accg[uf][rf][1];
                gp[2] = accg[uf][rf][2]; gp[3] = accg[uf][rf][3];
            }
        __syncthreads();                       // G visible; K/rt reads done

        // ---- phase 3a: stage V fp32 into kv region (swizzled for transposed read)
        #pragma unroll
        for (int it = 0; it < 8; ++it) {
            int ch = it*128 + tid;
            int t = ch >> 4, c4 = ch & 15;
            float4 v = *(const float4*)(heads + ((size_t)(j0 + t)*16 + b)*3072 + 2048 + n*64 + c4*4);
            *(float4*)(vf + t*64 + ((c4*4) ^ ((t & 7) << 2))) = v;
        }
        // ---- phase 3b: S = (AC+BD)*scale, mask, online softmax, P pair
        float p4[4][4];
        float smax = -3.0e38f;
        #pragma unroll
        for (int jf = 0; jf < 4; ++jf)
            #pragma unroll
            for (int rg = 0; rg < 4; ++rg) {
                int jl = 16*jf + lhi*4 + rg;
                int u  = (j0 + jl) - (i0 + iloc);
                int ucol = jl + 31 - iloc;
                int rsel = iloc + (u >= 514 ? 1 : 0);
                float sv = (accs[jf][rg] + gq[rsel*98 + ucol]) * 0.125f;
                if (j0 >= 512 && sdec[jl] == 0) sv = -1.0e9f;
                p4[jf][rg] = sv;
                smax = fmaxf(smax, sv);
            }
        smax = fmaxf(smax, __shfl_xor(smax, 16));
        smax = fmaxf(smax, __shfl_xor(smax, 32));
        float mnew  = fmaxf(m_run, smax);
        float alpha = expf(m_run - mnew);
        float psum = 0.f;
        #pragma unroll
        for (int jf = 0; jf < 4; ++jf)
            #pragma unroll
            for (int rg = 0; rg < 4; ++rg) {
                float e = expf(p4[jf][rg] - mnew);
                p4[jf][rg] = e; psum += e;
            }
        psum += __shfl_xor(psum, 16);
        psum += __shfl_xor(psum, 32);
        l_run = l_run*alpha + psum;
        m_run = mnew;
        #pragma unroll
        for (int df = 0; df < 4; ++df) {
            acc_o[df][0] *= alpha; acc_o[df][1] *= alpha;
            acc_o[df][2] *= alpha; acc_o[df][3] *= alpha;
        }
        #pragma unroll
        for (int jf = 0; jf < 4; ++jf) {
            ushort4 h4, l4;
            split2(p4[jf][0], h4.x, l4.x);
            split2(p4[jf][1], h4.y, l4.y);
            split2(p4[jf][2], h4.z, l4.z);
            split2(p4[jf][3], h4.w, l4.w);
            int joff = 16*jf + 4*lhi;
            int idx = iloc*64 + (((joff >> 3) ^ (iloc & 7)) << 3) + (joff & 7);
            *(ushort4*)(pH + idx) = h4; *(ushort4*)(pL + idx) = l4;
        }
        __syncthreads();                       // vf complete
        // ---- phase 3c: transpose V -> bf16 pair [d][j], stride 68 (in rt region)
        #pragma unroll
        for (int it = 0; it < 4; ++it) {
            int u = it*128 + tid;
            int d = u & 63, tc = u >> 6;
            ushort4 ha, hb, la, lb;
            float v0 = vf[(tc*8 + 0)*64 + (d ^ 0)];
            float v1 = vf[(tc*8 + 1)*64 + (d ^ 4)];
            float v2 = vf[(tc*8 + 2)*64 + (d ^ 8)];
            float v3 = vf[(tc*8 + 3)*64 + (d ^ 12)];
            float v4 = vf[(tc*8 + 4)*64 + (d ^ 16)];
            float v5 = vf[(tc*8 + 5)*64 + (d ^ 20)];
            float v6 = vf[(tc*8 + 6)*64 + (d ^ 24)];
            float v7 = vf[(tc*8 + 7)*64 + (d ^ 28)];
            split2(v0, ha.x, la.x); split2(v1, ha.y, la.y);
            split2(v2, ha.z, la.z); split2(v3, ha.w, la.w);
            split2(v4, hb.x, lb.x); split2(v5, hb.y, lb.y);
            split2(v6, hb.z, lb.z); split2(v7, hb.w, lb.w);
            int idx = d*68 + tc*8;
            *(ushort4*)(rtH + idx)     = ha; *(ushort4*)(rtH + idx + 4) = hb;
            *(ushort4*)(rtL + idx)     = la; *(ushort4*)(rtL + idx + 4) = lb;
        }
        __syncthreads();                       // V pair + P ready
        // ---- phase 4: PV (O^T += V^T . P^T)
        bf16x8 pBh[2], pBl[2];
        #pragma unroll
        for (int kc = 0; kc < 2; ++kc) {
            int row = 16*w + llo;
            int idx = row*64 + (((kc*4 + lhi) ^ (row & 7)) << 3);
            pBh[kc] = *(const bf16x8*)(pH + idx);
            pBl[kc] = *(const bf16x8*)(pL + idx);
        }
        union VU { ushort4 q[2]; bf16x8 v; };
        #pragma unroll
        for (int kc = 0; kc < 2; ++kc)
            #pragma unroll
            for (int df = 0; df < 4; ++df) {
                int d = 16*df + llo;
                int idx = d*68 + kc*32 + lhi*8;
                VU uh, ul;
                uh.q[0] = *(const ushort4*)(rtH + idx); uh.q[1] = *(const ushort4*)(rtH + idx + 4);
                ul.q[0] = *(const ushort4*)(rtL + idx); ul.q[1] = *(const ushort4*)(rtL + idx + 4);
                acc_o[df] = __builtin_amdgcn_mfma_f32_16x16x32_bf16(uh.v, pBh[kc], acc_o[df], 0, 0, 0);
                acc_o[df] = __builtin_amdgcn_mfma_f32_16x16x32_bf16(uh.v, pBl[kc], acc_o[df], 0, 0, 0);
                acc_o[df] = __builtin_amdgcn_mfma_f32_16x16x32_bf16(ul.v, pBh[kc], acc_o[df], 0, 0, 0);
            }
    }

    // epilogue: O^T fragment (rows d, col i) -> vec[i][n*64+d]
    float inv = 1.0f / l_run;
    #pragma unroll
    for (int df = 0; df < 4; ++df) {
        int d0 = 16*df + lhi*4;
        float4 o;
        o.x = acc_o[df][0]*inv; o.y = acc_o[df][1]*inv;
        o.z = acc_o[df][2]*inv; o.w = acc_o[df][3]*inv;
        *(float4*)(vec + ((size_t)(i0 + iloc)*16 + b)*1024 + n*64 + d0) = o;
    }
}

// ---------------- launch ----------------
extern "C" void kernel_launch(void* const* d_in, const int* in_sizes, int n_in,
                              void* d_out, int out_size, void* d_ws, size_t ws_size,
                              hipStream_t stream)
{
    (void)in_sizes; (void)n_in; (void)out_size; (void)ws_size;
    const int*   dec       = (const int*)  d_in[0];
    const float* mems      = (const float*)d_in[1];
    const float* rel_t_r   = (const float*)d_in[2];
    const float* rel_r_f   = (const float*)d_in[3];
    const float* theme_emb = (const float*)d_in[4];
    const float* role_emb  = (const float*)d_in[5];
    const float* form_emb  = (const float*)d_in[6];
    const float* word_emb  = (const float*)d_in[7];
    const float* theme_W   = (const float*)d_in[8];
    const float* theme_b   = (const float*)d_in[9];
    const float* r_w_bias  = (const float*)d_in[10];
    const float* r_r_bias  = (const float*)d_in[11];
    const float* qkv_W     = (const float*)d_in[12];
    const float* qkv_b     = (const float*)d_in[13];
    const float* r_W       = (const float*)d_in[14];
    const float* o_W       = (const float*)d_in[15];
    const float* o_b       = (const float*)d_in[16];
    const float* ln_att_g  = (const float*)d_in[17];
    const float* ln_att_b  = (const float*)d_in[18];
    const float* ln1_g     = (const float*)d_in[19];
    const float* ln1_b     = (const float*)d_in[20];
    const float* ffn_W1    = (const float*)d_in[21];
    const float* ffn_b1    = (const float*)d_in[22];
    const float* ffn_W2    = (const float*)d_in[23];
    const float* ffn_b2    = (const float*)d_in[24];
    const float* ln2_g     = (const float*)d_in[25];
    const float* ln2_b     = (const float*)d_in[26];

    float* ws      = (float*)d_ws;
    float* logits  = (float*)d_out;
    float* w_theme = ws + OFF_THEME;
    float* w_role  = ws + OFF_ROLE;
    float* w_tcat  = ws + OFF_TCAT;
    float* w_pos   = ws + OFF_POS;
    float* w_out   = ws + OFF_OUT;
    float* w_h     = ws + OFF_H;
    float* w_t2    = ws + OFF_T2;
    float* w_vec   = ws + OFF_VEC;
    float* w_pool  = ws + OFF_POOL;
    float* w_heads = ws + OFF_HEADS;
    unsigned* k2pk  = (unsigned*)(ws + OFF_H);    // spans w_h + w_t2 (contiguous), free during attn
    unsigned* rh2pk = (unsigned*)(ws + OFF_RH2);

    // theme pipeline
    k_role<<<64, 256, 0, stream>>>(rel_r_f, form_emb, role_emb, w_role);
    k_tcat<<<1000, 512, 0, stream>>>(rel_t_r, w_role, theme_emb, w_tcat);
    gemm_mfma<1, true, false, 0><<<dim3(8, 8), 256, 0, stream>>>(
        w_tcat, nullptr, 0, theme_W, theme_b, w_theme, nullptr, 1000, 1024, 512);

    k_pos<<<4096, 256, 0, stream>>>(w_pos);
    k_embed<<<8192, 256, 0, stream>>>(dec, word_emb, w_out);

    for (int i = 0; i < 8; ++i) {
        const float* memi = mems + (size_t)i*512*16*1024;
        // QKV: Q,V cols fp32 -> heads; K cols packed bf16 pair -> k2pk
        gemm_mfma<0, true, true, 2><<<dim3(24, 128), 256, 0, stream>>>(
            memi, w_out, 8192, qkv_W + (size_t)i*1024*3072, qkv_b + (size_t)i*3072,
            w_heads, k2pk, 16384, 3072, 1024);
        // rh = pos @ r_W -> packed bf16 pair
        gemm_mfma<0, false, false, 1><<<dim3(8, 8), 256, 0, stream>>>(
            w_pos, nullptr, 0, r_W + (size_t)i*1024*1024, nullptr, nullptr, rh2pk, 1024, 1024, 1024);
        // fused MFMA attention -> vec
        k_attn<<<dim3(16, 16, 16), 128, 0, stream>>>(w_heads, k2pk, rh2pk, r_w_bias, r_r_bias, dec, w_vec);
        // out-proj (overwrites k2pk upper half - safe, attn done)
        gemm_mfma<0, true, false, 0><<<dim3(8, 64), 256, 0, stream>>>(
            w_vec, nullptr, 0, o_W + (size_t)i*1024*1024, o_b + (size_t)i*1024,
            w_t2, nullptr, 8192, 1024, 1024);
        // h = LN(out + att)
        k_ln<true><<<8192, 256, 0, stream>>>(w_out, w_t2, ln_att_g + i*1024, ln_att_b + i*1024, w_h);
        // t = LN(h)
        k_ln<false><<<8192, 256, 0, stream>>>(w_h, nullptr, ln1_g + i*1024, ln1_b + i*1024, w_vec);
        // FFN1 (relu)
        gemm_mfma<2, true, false, 0><<<dim3(32, 64), 256, 0, stream>>>(
            w_vec, nullptr, 0, ffn_W1 + (size_t)i*1024*4096, ffn_b1 + (size_t)i*4096,
            w_heads, nullptr, 8192, 4096, 1024);
        // FFN2
        gemm_mfma<0, true, false, 0><<<dim3(8, 64), 256, 0, stream>>>(
            w_heads, nullptr, 0, ffn_W2 + (size_t)i*4096*1024, ffn_b2 + (size_t)i*1024,
            w_t2, nullptr, 8192, 1024, 4096);
        // out = LN(h + t)
        k_ln<true><<<8192, 256, 0, stream>>>(w_h, w_t2, ln2_g + i*1024, ln2_b + i*1024, w_out);
    }

    k_pool<<<64, 256, 0, stream>>>(dec, w_out, w_pool);
    k_logits<<<1000, 64, 0, stream>>>(w_pool, w_theme, logits);
}